// Round 1
// baseline (1115.500 us; speedup 1.0000x reference)
//
#include <hip/hip_runtime.h>

// Problem constants (B,S,D,H fixed by the reference)
#define Bb 8
#define Ss 1024
#define Dd 1024
#define Hh 16
#define DEPTHh 64
#define BSD (Bb*Ss*Dd)          // 8388608
#define DDn (Dd*Dd)             // 1048576

typedef __bf16 bf16x8 __attribute__((ext_vector_type(8)));
typedef float  f32x4  __attribute__((ext_vector_type(4)));

__device__ __forceinline__ unsigned short f2bf(float f){
  unsigned u = __float_as_uint(f);
  u = (u + 0x7fffu + ((u >> 16) & 1u)) >> 16;   // RNE
  return (unsigned short)u;
}
__device__ __forceinline__ float bf2f(unsigned short h){
  return __uint_as_float(((unsigned)h) << 16);
}

// ---------------- elementwise fp32 -> bf16 convert ----------------
__global__ __launch_bounds__(256) void cvt_bf16(const float4* __restrict__ in,
                                                ushort4* __restrict__ out, int n4){
  int i = blockIdx.x*256 + threadIdx.x;
  if (i >= n4) return;
  float4 v = in[i];
  ushort4 o; o.x = f2bf(v.x); o.y = f2bf(v.y); o.z = f2bf(v.z); o.w = f2bf(v.w);
  out[i] = o;
}

// ---------------- W [D,D] fp32 -> W^T [D,D] bf16 ----------------
__global__ __launch_bounds__(256) void transpose_w(const float* __restrict__ W,
                                                   ushort* __restrict__ WT){
  __shared__ float tl[32][33];
  int tx = threadIdx.x, ty = threadIdx.y;        // block (32,8)
  int bx = blockIdx.x*32, by = blockIdx.y*32;
  #pragma unroll
  for (int i=0;i<32;i+=8) tl[ty+i][tx] = W[(by+ty+i)*Dd + bx+tx];
  __syncthreads();
  #pragma unroll
  for (int i=0;i<32;i+=8) WT[(bx+ty+i)*Dd + by+tx] = f2bf(tl[tx][ty+i]);
}

// ---------------- vh [bh,s,64] -> vt [bh,64,s] (bf16) ----------------
__global__ __launch_bounds__(512) void transpose_v(const ushort* __restrict__ vh,
                                                   ushort* __restrict__ vt){
  __shared__ ushort tl[64][65];
  int tx = threadIdx.x, ty = threadIdx.y;        // block (64,8)
  long base = (long)blockIdx.y * 65536;          // bh * S*depth
  int s0 = blockIdx.x*64;
  #pragma unroll
  for (int i=0;i<64;i+=8) tl[ty+i][tx] = vh[base + (long)(s0+ty+i)*64 + tx];
  __syncthreads();
  #pragma unroll
  for (int i=0;i<64;i+=8) vt[base + (long)(ty+i)*1024 + s0 + tx] = tl[tx][ty+i];
}

// ---------------- BT-GEMM: C[m,n] = sum_k A[m,k]*B[n,k], bf16 MFMA ----------------
// 64x64 tile, 4 waves in 2x2 arrangement, each wave 2x2 of 16x16x32 MFMA tiles.
enum { M_PROJ=0, M_SCORES=1, M_PV=2, M_FINAL=3 };

template<int MODE>
__global__ __launch_bounds__(256) void gemm_bt(
    const ushort* __restrict__ Aall, const ushort* __restrict__ Ball,
    int lda, int ldb, int K, long sA, long sB,
    float* __restrict__ outf, ushort* __restrict__ outh,
    const float* __restrict__ aux)
{
  __shared__ ushort As[64][40];   // +8 pad: 80B row stride, 16B-aligned, ~2-way banks (free)
  __shared__ ushort Bs[64][40];
  const int z = blockIdx.z;
  const ushort* A  = Aall + (long)z*sA;
  const ushort* Bp = Ball + (long)z*sB;
  const int m0 = blockIdx.x*64, n0 = blockIdx.y*64;
  const int t = threadIdx.x;
  const int lane = t & 63, wave = t >> 6;
  const int wm = (wave>>1)*32, wn = (wave&1)*32;
  const int q = lane>>4, l16 = lane&15;
  const int srow = t>>2, scol = (t&3)*8;         // staging: 8 bf16 (16B) per thread

  f32x4 acc[2][2] = {};

  for (int k0=0; k0<K; k0+=32){
    uint4 av = *(const uint4*)(A  + (long)(m0+srow)*lda + k0 + scol);
    uint4 bv = *(const uint4*)(Bp + (long)(n0+srow)*ldb + k0 + scol);
    __syncthreads();
    *(uint4*)(&As[srow][scol]) = av;
    *(uint4*)(&Bs[srow][scol]) = bv;
    __syncthreads();
    bf16x8 a0 = *(const bf16x8*)(&As[wm      + l16][q*8]);
    bf16x8 a1 = *(const bf16x8*)(&As[wm + 16 + l16][q*8]);
    bf16x8 b0 = *(const bf16x8*)(&Bs[wn      + l16][q*8]);
    bf16x8 b1 = *(const bf16x8*)(&Bs[wn + 16 + l16][q*8]);
    acc[0][0] = __builtin_amdgcn_mfma_f32_16x16x32_bf16(a0,b0,acc[0][0],0,0,0);
    acc[0][1] = __builtin_amdgcn_mfma_f32_16x16x32_bf16(a0,b1,acc[0][1],0,0,0);
    acc[1][0] = __builtin_amdgcn_mfma_f32_16x16x32_bf16(a1,b0,acc[1][0],0,0,0);
    acc[1][1] = __builtin_amdgcn_mfma_f32_16x16x32_bf16(a1,b1,acc[1][1],0,0,0);
  }

  // C/D layout (m89/m91 verified): col = lane&15, row = (lane>>4)*4 + reg
  #pragma unroll
  for (int ti=0; ti<2; ti++)
  #pragma unroll
  for (int tj=0; tj<2; tj++)
  #pragma unroll
  for (int r=0; r<4; r++){
    float v = acc[ti][tj][r];
    const int row = m0 + wm + ti*16 + q*4 + r;
    const int col = n0 + wn + tj*16 + l16;
    if (MODE == M_PROJ){
      // row = b*S+s over [B*S, D]; write head-split [b,h,s,d] bf16
      v += aux[col];
      const int b = row>>10, s = row&1023, h = col>>6, d = col&63;
      outh[((long)((b*Hh + h)*Ss + s)<<6) + d] = f2bf(v);
    } else if (MODE == M_SCORES){
      // z = b*H+h; col = key index; scale + mask fused
      const int b = z>>4;
      v = v*0.125f + aux[(b<<10) + col] * (-1e9f);
      outh[((long)z<<20) + ((long)row<<10) + col] = f2bf(v);
    } else if (MODE == M_PV){
      // z = b*H+h; row = sq, col = d; write concat [b,s,h*64+d] bf16
      const int b = z>>4, h = z&15;
      outh[(((long)(b<<10) + row)<<10) + (h<<6) + col] = f2bf(v);
    } else { // M_FINAL
      v += aux[col];
      outf[(long)row*Dd + col] = v;
    }
  }
}

// ---------------- row softmax: bf16 scores (in place -> bf16 attn) + fp32 attn ----------------
__global__ __launch_bounds__(256) void softmax_rows(ushort* __restrict__ sc,
                                                    float* __restrict__ attn){
  const long row = (long)blockIdx.x*4 + (threadIdx.x>>6);   // wave per row
  const int lane = threadIdx.x & 63;
  ushort* srow = sc + (row<<10);
  const uint4* sv = (const uint4*)srow;
  uint4 c[2]; c[0] = sv[lane]; c[1] = sv[lane+64];
  float f[16];
  #pragma unroll
  for (int j=0;j<2;j++){
    const unsigned* wp = (const unsigned*)&c[j];
    #pragma unroll
    for (int i=0;i<4;i++){
      f[j*8+i*2]   = bf2f((unsigned short)(wp[i] & 0xffffu));
      f[j*8+i*2+1] = bf2f((unsigned short)(wp[i] >> 16));
    }
  }
  float m = -1e30f;
  #pragma unroll
  for (int i=0;i<16;i++) m = fmaxf(m, f[i]);
  #pragma unroll
  for (int off=32; off; off>>=1) m = fmaxf(m, __shfl_xor(m, off, 64));
  float ssum = 0.f;
  #pragma unroll
  for (int i=0;i<16;i++){ f[i] = __expf(f[i]-m); ssum += f[i]; }
  #pragma unroll
  for (int off=32; off; off>>=1) ssum += __shfl_xor(ssum, off, 64);
  const float inv = 1.0f / ssum;

  float4* arow = (float4*)(attn + (row<<10));
  #pragma unroll
  for (int j=0;j<2;j++){
    const int vidx = (j==0) ? lane : lane+64;
    float4 o0, o1;
    o0.x=f[j*8+0]*inv; o0.y=f[j*8+1]*inv; o0.z=f[j*8+2]*inv; o0.w=f[j*8+3]*inv;
    o1.x=f[j*8+4]*inv; o1.y=f[j*8+5]*inv; o1.z=f[j*8+6]*inv; o1.w=f[j*8+7]*inv;
    arow[vidx*2]   = o0;
    arow[vidx*2+1] = o1;
    unsigned w0 = (unsigned)f2bf(o0.x) | ((unsigned)f2bf(o0.y)<<16);
    unsigned w1 = (unsigned)f2bf(o0.z) | ((unsigned)f2bf(o0.w)<<16);
    unsigned w2 = (unsigned)f2bf(o1.x) | ((unsigned)f2bf(o1.y)<<16);
    unsigned w3 = (unsigned)f2bf(o1.z) | ((unsigned)f2bf(o1.w)<<16);
    uint4 ob; ob.x=w0; ob.y=w1; ob.z=w2; ob.w=w3;
    ((uint4*)srow)[vidx] = ob;
  }
}

extern "C" void kernel_launch(void* const* d_in, const int* in_sizes, int n_in,
                              void* d_out, int out_size, void* d_ws, size_t ws_size,
                              hipStream_t stream)
{
  (void)in_sizes; (void)n_in; (void)out_size; (void)ws_size;
  const float* Q    = (const float*)d_in[0];
  const float* Kin  = (const float*)d_in[1];
  const float* V    = (const float*)d_in[2];
  const float* mask = (const float*)d_in[3];
  const float* Wq   = (const float*)d_in[4];
  const float* bq   = (const float*)d_in[5];
  const float* Wk   = (const float*)d_in[6];
  const float* bk   = (const float*)d_in[7];
  const float* Wv   = (const float*)d_in[8];
  const float* bv   = (const float*)d_in[9];
  const float* Wo   = (const float*)d_in[10];
  const float* bo   = (const float*)d_in[11];
  float* out    = (float*)d_out;
  float* attn_f = out + (long)BSD;

  // Workspace layout (ushort elements). Total = 6*BSD + 4*DD + B*H*S*S = ~377 MB.
  ushort* ws     = (ushort*)d_ws;
  ushort* Xq     = ws;                 // bf16 Q input; reused as concat buffer later
  ushort* Xk     = Xq  + (long)BSD;
  ushort* Xv     = Xk  + (long)BSD;
  ushort* WqT    = Xv  + (long)BSD;
  ushort* WkT    = WqT + (long)DDn;
  ushort* WvT    = WkT + (long)DDn;
  ushort* WoT    = WvT + (long)DDn;
  ushort* qh     = WoT + (long)DDn;    // [b,h,s,64] bf16
  ushort* kh     = qh  + (long)BSD;
  ushort* vt     = kh  + (long)BSD;    // [b,h,64,s] bf16
  ushort* attn_h = vt  + (long)BSD;    // [b,h,s,s] bf16 scores -> attn (in place)
  ushort* vh     = attn_h;             // temp [b,h,s,64]; clobbered by scores later
  ushort* concat = Xq;                 // [b,s,D] bf16, reuse of Xq

  // 1. fp32 -> bf16 input converts
  cvt_bf16<<<dim3(BSD/4/256), 256, 0, stream>>>((const float4*)Q,   (ushort4*)Xq, BSD/4);
  cvt_bf16<<<dim3(BSD/4/256), 256, 0, stream>>>((const float4*)Kin, (ushort4*)Xk, BSD/4);
  cvt_bf16<<<dim3(BSD/4/256), 256, 0, stream>>>((const float4*)V,   (ushort4*)Xv, BSD/4);

  // 2. weight transposes (fp32 -> bf16 W^T)
  transpose_w<<<dim3(32,32), dim3(32,8), 0, stream>>>(Wq, WqT);
  transpose_w<<<dim3(32,32), dim3(32,8), 0, stream>>>(Wk, WkT);
  transpose_w<<<dim3(32,32), dim3(32,8), 0, stream>>>(Wv, WvT);
  transpose_w<<<dim3(32,32), dim3(32,8), 0, stream>>>(Wo, WoT);

  // 3. projections: [8192,1024] @ W^T -> head-split bf16
  gemm_bt<M_PROJ><<<dim3(128,16,1), 256, 0, stream>>>(Xq, WqT, Dd, Dd, Dd, 0,0, nullptr, qh, bq);
  gemm_bt<M_PROJ><<<dim3(128,16,1), 256, 0, stream>>>(Xk, WkT, Dd, Dd, Dd, 0,0, nullptr, kh, bk);
  gemm_bt<M_PROJ><<<dim3(128,16,1), 256, 0, stream>>>(Xv, WvT, Dd, Dd, Dd, 0,0, nullptr, vh, bv);

  // 3b. v [bh,s,64] -> v^T [bh,64,s]
  transpose_v<<<dim3(16,128), dim3(64,8), 0, stream>>>(vh, vt);

  // 4. scores = q k^T * 1/8 + mask*(-1e9), bf16 to ws
  gemm_bt<M_SCORES><<<dim3(16,16,128), 256, 0, stream>>>(qh, kh, 64, 64, 64,
                                                         65536, 65536, nullptr, attn_h, mask);

  // 5. row softmax: fp32 attn to d_out, bf16 attn in place
  softmax_rows<<<dim3(32768), 256, 0, stream>>>(attn_h, attn_f);

  // 6. out_head = attn @ v : BT-GEMM vs vt, write bf16 concat [b,s,D]
  gemm_bt<M_PV><<<dim3(16,1,128), 256, 0, stream>>>(attn_h, vt, 1024, 1024, 1024,
                                                    1048576, 65536, nullptr, concat, nullptr);

  // 7. final: concat @ Wo + bo -> fp32 out
  gemm_bt<M_FINAL><<<dim3(128,16,1), 256, 0, stream>>>(concat, WoT, Dd, Dd, Dd,
                                                       0,0, out, nullptr, bo);
}